// Round 15
// baseline (368.640 us; speedup 1.0000x reference)
//
#include <hip/hip_runtime.h>
#include <stdint.h>

#define TOKENS 8192
#define INF    4096
#define OUTF   4096
#define NT     64   // K-tiles of BK=64

typedef __bf16 bf16x8 __attribute__((ext_vector_type(8)));
typedef float  f32x4  __attribute__((ext_vector_type(4)));
typedef unsigned short ushort_t;

// ---------- fp32 -> bf16 (RNE) ----------
__device__ __forceinline__ unsigned short f2bf(float f) {
  union { float f; unsigned int u; } v;
  v.f = f;
  unsigned int r = v.u + 0x7fffu + ((v.u >> 16) & 1u);
  return (unsigned short)(r >> 16);
}

__global__ void l2b_conv_x(const float* __restrict__ x,
                           unsigned short* __restrict__ xb, int n4) {
  int idx = blockIdx.x * blockDim.x + threadIdx.x;
  int stride = gridDim.x * blockDim.x;
  for (int i = idx; i < n4; i += stride) {
    float4 v = reinterpret_cast<const float4*>(x)[i];
    ushort4 o;
    o.x = f2bf(v.x); o.y = f2bf(v.y); o.z = f2bf(v.z); o.w = f2bf(v.w);
    reinterpret_cast<ushort4*>(xb)[i] = o;
  }
}

__global__ void l2b_conv_w(const int* __restrict__ w,
                           unsigned short* __restrict__ wb, int n4) {
  int idx = blockIdx.x * blockDim.x + threadIdx.x;
  int stride = gridDim.x * blockDim.x;
  for (int i = idx; i < n4; i += stride) {
    int4 v = reinterpret_cast<const int4*>(w)[i];
    ushort4 o;  // {-2,-1,0,1}: exact in bf16
    o.x = f2bf((float)v.x); o.y = f2bf((float)v.y);
    o.z = f2bf((float)v.z); o.w = f2bf((float)v.w);
    reinterpret_cast<ushort4*>(wb)[i] = o;
  }
}

// ---------- async global->LDS, 16B/lane (dest = wave base + lane*16) ---------
__device__ __forceinline__ void gload_lds16(const ushort_t* g, ushort_t* l) {
  auto gp = reinterpret_cast<__attribute__((address_space(1))) unsigned int*>(
      reinterpret_cast<uintptr_t>(g));
  auto lp = reinterpret_cast<__attribute__((address_space(3))) unsigned int*>(
      reinterpret_cast<uintptr_t>(l));
  __builtin_amdgcn_global_load_lds(gp, lp, 16, 0, 0);
}

// ---------- full-bank swizzle: byte ^= (row&7)<<4 within [128][64] slot ------
// R11/R13-proven (0 conflicts, toolchain-robust): per b128 frag read the 8
// 16B positions are each hit by exactly 8 lanes -> 1KiB minimum.
__device__ __forceinline__ bf16x8 ldsRd(const ushort_t* slot, int row, int colb) {
  int off = ((row << 7) | colb) ^ ((row & 7) << 4);
  return *reinterpret_cast<const bf16x8*>(
      reinterpret_cast<const char*>(slot) + off);
}

// stage one 128x64 slot (16 KiB): 4 gloads/thread, linear LDS dest,
// inverse-swizzled per-lane global source (ge[] in elements)
__device__ __forceinline__ void stage_slot(const ushort_t* __restrict__ src,
                                           ushort_t* slot, int wid,
                                           const int (&ge)[4]) {
#pragma unroll
  for (int r = 0; r < 4; ++r)
    gload_lds16(src + ge[r], slot + r * 2048 + wid * 512);
}

__device__ __forceinline__ f32x4 mfma(bf16x8 a, bf16x8 b, f32x4 c) {
  return __builtin_amdgcn_mfma_f32_16x16x32_bf16(a, b, c, 0, 0, 0);
}

// ============ one K-tile: 2 phases; provably race-free staging ===============
// ph1: read ALL 16 frags of tile t from slot[p]; lgkm0+SB; 16 MFMA (kh0); BAR.
//      -> every wave's reads of slot[p] complete before ANY wave passes BAR.
// ph2: stage 8 gloads -> slot[p] (tile t+2, safe by the BAR above);
//      16 MFMA (kh1, reg operands); vmcnt(8) forces own t+1 stages; BAR joins
//      all waves -> tile t+1 published (R11's publication pattern).
template <int VMB, bool STG>
__device__ __forceinline__ void ktile(
    const ushort_t* __restrict__ A, const ushort_t* __restrict__ B,
    int rowBlk, int colBlk, int t,
    const ushort_t* rA, const ushort_t* rB,   // slot[p] (read)
    ushort_t* wA, ushort_t* wB,               // slot[p] (stage t+2)
    f32x4 (&acc)[4][4], int ar, int br, int fkq, int wid, const int (&ge)[4]) {
  bf16x8 a[4][2], b[4][2];
  // ---- phase 1: read everything, compute kh0 ----
#pragma unroll
  for (int m = 0; m < 4; ++m) {
    a[m][0] = ldsRd(rA, ar + m * 16, fkq);
    a[m][1] = ldsRd(rA, ar + m * 16, 64 + fkq);
  }
#pragma unroll
  for (int n = 0; n < 4; ++n) {
    b[n][0] = ldsRd(rB, br + n * 16, fkq);
    b[n][1] = ldsRd(rB, br + n * 16, 64 + fkq);
  }
  asm volatile("s_waitcnt lgkmcnt(0)" ::: "memory");
  __builtin_amdgcn_sched_barrier(0);
  __builtin_amdgcn_s_setprio(1);
#pragma unroll
  for (int m = 0; m < 4; ++m)
#pragma unroll
    for (int n = 0; n < 4; ++n)
      acc[m][n] = mfma(a[m][0], b[n][0], acc[m][n]);
  __builtin_amdgcn_s_setprio(0);
  __builtin_amdgcn_s_barrier();   // all reads of slot[p] drained block-wide
  // ---- phase 2: stage t+2 into slot[p]; compute kh1 ----
  if (STG) {
    stage_slot(A + (size_t)rowBlk * INF + (t + 2) * 64, wA, wid, ge);
    stage_slot(B + (size_t)colBlk * INF + (t + 2) * 64, wB, wid, ge);
  }
  __builtin_amdgcn_s_setprio(1);
#pragma unroll
  for (int m = 0; m < 4; ++m)
#pragma unroll
    for (int n = 0; n < 4; ++n)
      acc[m][n] = mfma(a[m][1], b[n][1], acc[m][n]);
  __builtin_amdgcn_s_setprio(0);
  if (VMB == 8) asm volatile("s_waitcnt vmcnt(8)" ::: "memory");
  if (VMB == 0) asm volatile("s_waitcnt vmcnt(0)" ::: "memory");
  __builtin_amdgcn_s_barrier();   // publish tile t+1 to all waves
}

// ====== 128x128 GEMM, BK=64, 64 KiB LDS -> 2 blocks/CU (cross-block overlap) =
__global__ __launch_bounds__(256, 2) void l2b_gemmD(
    const ushort_t* __restrict__ A, const ushort_t* __restrict__ B,
    const float* __restrict__ scale, const float* __restrict__ bias,
    float* __restrict__ C) {
  extern __shared__ ushort_t smem[];  // 64 KiB = 4 slots of 16 KiB
  // named scalar pointers (pointer ARRAYS of __shared__ fail to compile on
  // gfx950: "unsupported addrspacecast static initializer" — R14 lesson)
  ushort_t* sA0 = smem;          ushort_t* sA1 = smem + 8192;
  ushort_t* sB0 = smem + 16384;  ushort_t* sB1 = smem + 24576;

  const int tid  = threadIdx.x;
  const int lane = tid & 63;
  const int wid  = tid >> 6;              // 0..3
  const int wm = wid >> 1, wn = wid & 1;  // 2x2 wave grid, wave tile 64x64
  const int fr = lane & 15, fk = lane >> 4;
  const int ar = wm * 64 + fr;
  const int br = wn * 64 + fr;
  const int fkq = fk * 16;                // kh0 byte col; kh1 = 64 + fkq

  // XCD-aware swizzle (nwg=2048, divisible by 8)
  const int bid = (int)blockIdx.x;
  const int idx = (bid & 7) * 256 + (bid >> 3);
  const int bm = idx >> 5, bn = idx & 31;     // 64 x 32 tiles
  const int rowBlk = bm * 128, colBlk = bn * 128;

  // inverse-swizzled per-thread global element offsets for the 4 stage rounds:
  // physical byte P (linear write) holds logical byte P ^ ((row&7)<<4)
  int ge[4];
#pragma unroll
  for (int r = 0; r < 4; ++r) {
    const int P = r * 4096 + tid * 16;
    const int row = P >> 7;
    const int col = (P & 127) ^ ((row & 7) << 4);
    ge[r] = row * INF + (col >> 1);
  }

  // ---- prologue: stage tiles 0 and 1; vmcnt(8) -> tile 0 landed ----
  stage_slot(A + (size_t)rowBlk * INF,      sA0, wid, ge);
  stage_slot(B + (size_t)colBlk * INF,      sB0, wid, ge);
  stage_slot(A + (size_t)rowBlk * INF + 64, sA1, wid, ge);
  stage_slot(B + (size_t)colBlk * INF + 64, sB1, wid, ge);
  asm volatile("s_waitcnt vmcnt(8)" ::: "memory");
  __builtin_amdgcn_s_barrier();

  f32x4 acc[4][4] = {};

#pragma unroll 1
  for (int t = 0; t < NT - 2; ++t) {            // tiles 0..61
    const int p = t & 1;
    const ushort_t* rA = p ? sA1 : sA0;
    const ushort_t* rB = p ? sB1 : sB0;
    ushort_t* wA = p ? sA1 : sA0;
    ushort_t* wB = p ? sB1 : sB0;
    ktile<8, true>(A, B, rowBlk, colBlk, t,
        rA, rB, wA, wB, acc, ar, br, fkq, wid, ge);
  }
  // tile 62: no stage; vmcnt(0) forces tile 63 (issued at tile 61's ph2)
  ktile<0, false>(A, B, rowBlk, colBlk, NT - 2,
      sA0, sB0, sA0, sB0, acc, ar, br, fkq, wid, ge);
  // tile 63: compute only
  ktile<-1, false>(A, B, rowBlk, colBlk, NT - 1,
      sA1, sB1, sA1, sB1, acc, ar, br, fkq, wid, ge);

  // ---- epilogue (R1-verified 128^2 mapping): col=lane&15, row=(lane>>4)*4+j
  const float s = scale[0];
#pragma unroll
  for (int n = 0; n < 4; ++n) {
    const int col = colBlk + wn * 64 + n * 16 + fr;
    const float bv = bias[col];
#pragma unroll
    for (int m = 0; m < 4; ++m) {
      const int row = rowBlk + wm * 64 + m * 16 + fk * 4;
#pragma unroll
      for (int j = 0; j < 4; ++j)
        C[(size_t)(row + j) * OUTF + col] = acc[m][n][j] * s + bv;
    }
  }
}

// ---------------- fallback: R1 128x128 m97-structure GEMM -------------------
__global__ __launch_bounds__(256) void l2b_gemm(
    const ushort_t* __restrict__ A, const ushort_t* __restrict__ B,
    const float* __restrict__ scale, const float* __restrict__ bias,
    float* __restrict__ C) {
  constexpr int K = INF;
  constexpr int N = OUTF;
  __shared__ __align__(16) ushort_t ldsA[128 * 32];
  __shared__ __align__(16) ushort_t ldsB[128 * 32];
  const int tid = threadIdx.x;
  const int lane = tid & 63;
  const int wid = tid >> 6;
  const int wm = wid >> 1, wn = wid & 1;
  const int bm = blockIdx.x >> 5, bn = blockIdx.x & 31;
  const int row0 = bm * 128, col0 = bn * 128;
  const int lr = lane >> 4, lc = lane & 15;
  f32x4 acc[4][4] = {};
  for (int k0 = 0; k0 < K; k0 += 32) {
#pragma unroll
    for (int i = 0; i < 2; ++i) {
      const int idx = i * 256 + tid;
      const int r = idx >> 2;
      const int c = (idx & 3) * 8;
      ushort_t* lbaseA = ldsA + i * 2048 + wid * 512;
      ushort_t* lbaseB = ldsB + i * 2048 + wid * 512;
      gload_lds16(A + (size_t)(row0 + r) * K + (k0 + c), lbaseA);
      gload_lds16(B + (size_t)(col0 + r) * K + (k0 + c), lbaseB);
    }
    __syncthreads();
    bf16x8 af[4], bfr[4];
#pragma unroll
    for (int m = 0; m < 4; ++m)
      af[m] = *reinterpret_cast<const bf16x8*>(
          &ldsA[(wm * 64 + m * 16 + lc) * 32 + lr * 8]);
#pragma unroll
    for (int n = 0; n < 4; ++n)
      bfr[n] = *reinterpret_cast<const bf16x8*>(
          &ldsB[(wn * 64 + n * 16 + lc) * 32 + lr * 8]);
#pragma unroll
    for (int m = 0; m < 4; ++m)
#pragma unroll
      for (int n = 0; n < 4; ++n)
        acc[m][n] = mfma(af[m], bfr[n], acc[m][n]);
    __syncthreads();
  }
  const float s = scale[0];
#pragma unroll
  for (int n = 0; n < 4; ++n) {
    const int col = col0 + wn * 64 + n * 16 + lc;
    const float bv = bias[col];
#pragma unroll
    for (int m = 0; m < 4; ++m) {
      const int row = row0 + wm * 64 + m * 16 + lr * 4;
#pragma unroll
      for (int i = 0; i < 4; ++i)
        C[(size_t)(row + i) * N + col] = acc[m][n][i] * s + bv;
    }
  }
}

__global__ void l2b_naive(const float* __restrict__ x, const int* __restrict__ w,
                          const float* __restrict__ scale,
                          const float* __restrict__ bias,
                          float* __restrict__ out) {
  const int o = blockIdx.x * blockDim.x + threadIdx.x;
  if (o >= TOKENS * OUTF) return;
  const int t = o / OUTF;
  const int n = o - t * OUTF;
  const float* xr = x + (size_t)t * INF;
  const int* wr = w + (size_t)n * INF;
  float acc = 0.f;
  for (int k = 0; k < INF; ++k) acc += xr[k] * (float)wr[k];
  out[o] = acc * scale[0] + bias[n];
}

extern "C" void kernel_launch(void* const* d_in, const int* in_sizes, int n_in,
                              void* d_out, int out_size, void* d_ws, size_t ws_size,
                              hipStream_t stream) {
  const float* x     = (const float*)d_in[0];
  const int*   wq    = (const int*)d_in[1];
  const float* scale = (const float*)d_in[2];
  const float* bias  = (const float*)d_in[3];
  float* out = (float*)d_out;

  const size_t xbytes = (size_t)TOKENS * INF * 2;
  const size_t wbytes = (size_t)OUTF * INF * 2;

  if (ws_size >= xbytes + wbytes) {
    unsigned short* xb = (unsigned short*)d_ws;
    unsigned short* wb = (unsigned short*)((char*)d_ws + xbytes);
    l2b_conv_x<<<2048, 256, 0, stream>>>(x, xb, TOKENS * INF / 4);
    l2b_conv_w<<<2048, 256, 0, stream>>>(wq, wb, OUTF * INF / 4);

    hipError_t e = hipFuncSetAttribute(
        reinterpret_cast<const void*>(l2b_gemmD),
        hipFuncAttributeMaxDynamicSharedMemorySize, 65536);
    if (e == hipSuccess) {
      l2b_gemmD<<<dim3((TOKENS / 128) * (OUTF / 128)), 256, 65536, stream>>>(
          xb, wb, scale, bias, out);
    } else {
      l2b_gemm<<<dim3((TOKENS / 128) * (OUTF / 128)), 256, 0, stream>>>(
          xb, wb, scale, bias, out);
    }
  } else {
    l2b_naive<<<(TOKENS * OUTF + 255) / 256, 256, 0, stream>>>(
        x, wq, scale, bias, out);
  }
}

// Round 16
// 263.245 us; speedup vs baseline: 1.4004x; 1.4004x over previous
//
#include <hip/hip_runtime.h>
#include <stdint.h>

#define TOKENS 8192
#define INF    4096
#define OUTF   4096
#define NT     64   // K-tiles of BK=64

typedef __bf16 bf16x8 __attribute__((ext_vector_type(8)));
typedef float  f32x4  __attribute__((ext_vector_type(4)));
typedef unsigned short ushort_t;

// ---------- fp32 -> bf16 (RNE) ----------
__device__ __forceinline__ unsigned short f2bf(float f) {
  union { float f; unsigned int u; } v;
  v.f = f;
  unsigned int r = v.u + 0x7fffu + ((v.u >> 16) & 1u);
  return (unsigned short)(r >> 16);
}

__global__ void l2b_conv_x(const float* __restrict__ x,
                           unsigned short* __restrict__ xb, int n4) {
  int idx = blockIdx.x * blockDim.x + threadIdx.x;
  int stride = gridDim.x * blockDim.x;
  for (int i = idx; i < n4; i += stride) {
    float4 v = reinterpret_cast<const float4*>(x)[i];
    ushort4 o;
    o.x = f2bf(v.x); o.y = f2bf(v.y); o.z = f2bf(v.z); o.w = f2bf(v.w);
    reinterpret_cast<ushort4*>(xb)[i] = o;
  }
}

__global__ void l2b_conv_w(const int* __restrict__ w,
                           unsigned short* __restrict__ wb, int n4) {
  int idx = blockIdx.x * blockDim.x + threadIdx.x;
  int stride = gridDim.x * blockDim.x;
  for (int i = idx; i < n4; i += stride) {
    int4 v = reinterpret_cast<const int4*>(w)[i];
    ushort4 o;  // {-2,-1,0,1}: exact in bf16
    o.x = f2bf((float)v.x); o.y = f2bf((float)v.y);
    o.z = f2bf((float)v.z); o.w = f2bf((float)v.w);
    reinterpret_cast<ushort4*>(wb)[i] = o;
  }
}

// ---------- async global->LDS, 16B/lane (dest = wave base + lane*16) ---------
__device__ __forceinline__ void gload_lds16(const ushort_t* g, ushort_t* l) {
  auto gp = reinterpret_cast<__attribute__((address_space(1))) unsigned int*>(
      reinterpret_cast<uintptr_t>(g));
  auto lp = reinterpret_cast<__attribute__((address_space(3))) unsigned int*>(
      reinterpret_cast<uintptr_t>(l));
  __builtin_amdgcn_global_load_lds(gp, lp, 16, 0, 0);
}

// ---------- full-bank swizzle: byte ^= (row&7)<<4 within [128][64] half-slot -
// Per ds_read_b128 (16 rows x 4 chunk-cols), position (kh*4+fk)^(r&7) covers
// all 8 x 16B positions 8x each -> 8 lanes/bank = 1KiB minimum, conflict-free
// by lane math (independent of compiler instruction selection). [R11/R13: 0]
__device__ __forceinline__ bf16x8 ldsRd(const ushort_t* slot, int row, int colb) {
  int off = ((row << 7) | colb) ^ ((row & 7) << 4);
  return *reinterpret_cast<const bf16x8*>(
      reinterpret_cast<const char*>(slot) + off);
}

// stage one 128x64 half-tile: 2 gloads/thread, linear LDS dest,
// inverse-swizzled per-lane global source (ge0/ge1 in elements)
__device__ __forceinline__ void stage_half(const ushort_t* __restrict__ src,
                                           ushort_t* slot, int wid,
                                           int ge0, int ge1) {
  gload_lds16(src + ge0, slot + wid * 512);
  gload_lds16(src + ge1, slot + 4096 + wid * 512);
}

__device__ __forceinline__ f32x4 mfma(bf16x8 a, bf16x8 b, f32x4 c) {
  return __builtin_amdgcn_mfma_f32_16x16x32_bf16(a, b, c, 0, 0, 0);
}

template <int N>
__device__ __forceinline__ void vmwait() {
  if constexpr (N == 4)      asm volatile("s_waitcnt vmcnt(4)" ::: "memory");
  else if constexpr (N == 0) asm volatile("s_waitcnt vmcnt(0)" ::: "memory");
}

#define PHASE_SYNC()                                            \
  __builtin_amdgcn_s_barrier();                                 \
  asm volatile("s_waitcnt lgkmcnt(0)" ::: "memory");            \
  __builtin_amdgcn_sched_barrier(0);                            \
  __builtin_amdgcn_s_setprio(1)

#define PHASE_END() __builtin_amdgcn_s_setprio(0)

// ---------------- one K-tile: 4 phases, 16 MFMA each -------------------------
// reads: ph1 (A0,B0) -> acc[0..3][0..1]; ph2 (A0,B1) -> acc[0..3][2..3];
//        ph3 (A1,B1) -> acc[4..7][2..3]; ph4 (A1,B0) -> acc[4..7][0..1]
// stages: ph1 A1(t+1)->oA1; ph2 B0(t+1)->oB0; ph3 A0(t+2)->rA0; ph4 B1(t+2)->rB1
// vmcnt(4) at tile end: 12 outstanding -> forces the 8 oldest = ALL of tile
// (t+1)'s halves; leaves A0(t+2),B1(t+2) in flight (R3/R11-proven ledger).
template <int VMB, bool STG1, bool STG2>
__device__ __forceinline__ void ktile(
    const ushort_t* __restrict__ A, const ushort_t* __restrict__ B,
    int rowBlk, int colBlk, int t,
    ushort_t* rA0, ushort_t* rA1, ushort_t* rB0, ushort_t* rB1,
    ushort_t* oA1, ushort_t* oB0,
    f32x4 (&acc)[8][4], int ar, int br, int fk, int wid, int ge0, int ge1) {
  bf16x8 a[4][2], b[2][2];
  // ---- phase 1 ----
#pragma unroll
  for (int m = 0; m < 4; ++m) {
    a[m][0] = ldsRd(rA0, ar + m * 16, fk * 16);
    a[m][1] = ldsRd(rA0, ar + m * 16, 64 + fk * 16);
  }
#pragma unroll
  for (int n = 0; n < 2; ++n) {
    b[n][0] = ldsRd(rB0, br + n * 16, fk * 16);
    b[n][1] = ldsRd(rB0, br + n * 16, 64 + fk * 16);
  }
  if (STG1)
    stage_half(A + (size_t)(rowBlk + 128) * INF + (t + 1) * 64, oA1, wid, ge0, ge1);
  PHASE_SYNC();
#pragma unroll
  for (int m = 0; m < 4; ++m)
#pragma unroll
    for (int n = 0; n < 2; ++n) {
      acc[m][n] = mfma(a[m][0], b[n][0], acc[m][n]);
      acc[m][n] = mfma(a[m][1], b[n][1], acc[m][n]);
    }
  PHASE_END();
  __builtin_amdgcn_s_barrier();
  // ---- phase 2 ----
#pragma unroll
  for (int n = 0; n < 2; ++n) {
    b[n][0] = ldsRd(rB1, br + n * 16, fk * 16);
    b[n][1] = ldsRd(rB1, br + n * 16, 64 + fk * 16);
  }
  if (STG1)
    stage_half(B + (size_t)colBlk * INF + (t + 1) * 64, oB0, wid, ge0, ge1);
  PHASE_SYNC();
#pragma unroll
  for (int m = 0; m < 4; ++m)
#pragma unroll
    for (int n = 0; n < 2; ++n) {
      acc[m][2 + n] = mfma(a[m][0], b[n][0], acc[m][2 + n]);
      acc[m][2 + n] = mfma(a[m][1], b[n][1], acc[m][2 + n]);
    }
  PHASE_END();
  __builtin_amdgcn_s_barrier();
  // ---- phase 3 (B1 frags reused from regs) ----
#pragma unroll
  for (int m = 0; m < 4; ++m) {
    a[m][0] = ldsRd(rA1, ar + m * 16, fk * 16);
    a[m][1] = ldsRd(rA1, ar + m * 16, 64 + fk * 16);
  }
  if (STG2)
    stage_half(A + (size_t)rowBlk * INF + (t + 2) * 64, rA0, wid, ge0, ge1);
  PHASE_SYNC();
#pragma unroll
  for (int m = 0; m < 4; ++m)
#pragma unroll
    for (int n = 0; n < 2; ++n) {
      acc[4 + m][2 + n] = mfma(a[m][0], b[n][0], acc[4 + m][2 + n]);
      acc[4 + m][2 + n] = mfma(a[m][1], b[n][1], acc[4 + m][2 + n]);
    }
  PHASE_END();
  __builtin_amdgcn_s_barrier();
  // ---- phase 4 (re-read B0; forced by the 256-reg unified cap) ----
#pragma unroll
  for (int n = 0; n < 2; ++n) {
    b[n][0] = ldsRd(rB0, br + n * 16, fk * 16);
    b[n][1] = ldsRd(rB0, br + n * 16, 64 + fk * 16);
  }
  if (STG2)
    stage_half(B + (size_t)(colBlk + 128) * INF + (t + 2) * 64, rB1, wid, ge0, ge1);
  PHASE_SYNC();
#pragma unroll
  for (int m = 0; m < 4; ++m)
#pragma unroll
    for (int n = 0; n < 2; ++n) {
      acc[4 + m][n] = mfma(a[m][0], b[n][0], acc[4 + m][n]);
      acc[4 + m][n] = mfma(a[m][1], b[n][1], acc[4 + m][n]);
    }
  PHASE_END();
  if (VMB >= 0) vmwait<VMB >= 0 ? VMB : 0>();
  __builtin_amdgcn_s_barrier();
}

// ---------------- 256x256 8-phase GEMM: C[t][o] = A[t][:] . B[o][:] ----------
__global__ __launch_bounds__(512, 2) void l2b_gemm8(
    const ushort_t* __restrict__ A, const ushort_t* __restrict__ B,
    const float* __restrict__ scale, const float* __restrict__ bias,
    float* __restrict__ C) {
  extern __shared__ ushort_t smem[];  // 128 KiB = 8 half-slots of 16 KiB
  ushort_t* sA00 = smem;              ushort_t* sA01 = smem + 8192;
  ushort_t* sA10 = smem + 16384;      ushort_t* sA11 = smem + 24576;
  ushort_t* sB00 = smem + 32768;      ushort_t* sB01 = smem + 40960;
  ushort_t* sB10 = smem + 49152;      ushort_t* sB11 = smem + 57344;

  const int tid  = threadIdx.x;
  const int lane = tid & 63;
  const int wid  = tid >> 6;              // 0..7
  const int wm = wid >> 2, wn = wid & 3;  // 2x4 wave grid
  const int fr = lane & 15, fk = lane >> 4;
  const int ar = wm * 64 + fr;            // a-frag row within half
  const int br = wn * 32 + fr;            // b-frag row within half

  // XCD-aware swizzle (nwg=512, divisible by 8)
  const int bid = (int)blockIdx.x;
  const int idx = (bid & 7) * 64 + (bid >> 3);
  const int bm = idx >> 4, bn = idx & 15;
  const int rowBlk = bm * 256, colBlk = bn * 256;

  // inverse-swizzled per-lane global element offsets for the 2 staging rounds:
  // physical byte P (linear write) must hold logical byte P ^ ((row&7)<<4)
  const int ob0 = wid * 1024 + lane * 16;       // physical byte off, round 0
  const int ob1 = 8192 + ob0;                   // round 1
  const int r0 = ob0 >> 7, r1 = ob1 >> 7;
  const int c0 = (ob0 & 127) ^ ((r0 & 7) << 4);
  const int c1 = (ob1 & 127) ^ ((r1 & 7) << 4);
  const int ge0 = r0 * INF + (c0 >> 1);
  const int ge1 = r1 * INF + (c1 >> 1);

  // ---- prologue: steady-state stream order A0(0),B1(0),A1(0),B0(0),A0(1),B1(1)
  stage_half(A + (size_t)rowBlk * INF,               sA00, wid, ge0, ge1);
  stage_half(B + (size_t)(colBlk + 128) * INF,       sB01, wid, ge0, ge1);
  stage_half(A + (size_t)(rowBlk + 128) * INF,       sA01, wid, ge0, ge1);
  stage_half(B + (size_t)colBlk * INF,               sB00, wid, ge0, ge1);
  stage_half(A + (size_t)rowBlk * INF + 64,          sA10, wid, ge0, ge1);
  stage_half(B + (size_t)(colBlk + 128) * INF + 64,  sB11, wid, ge0, ge1);
  asm volatile("s_waitcnt vmcnt(4)" ::: "memory");   // tile 0 landed
  __builtin_amdgcn_s_barrier();

  f32x4 acc[8][4] = {};

#pragma unroll 1
  for (int i = 0; i < 31; ++i) {                     // tiles 0..61
    const int t = 2 * i;
    ktile<4, true, true>(A, B, rowBlk, colBlk, t,
        sA00, sA01, sB00, sB01, sA11, sB10,
        acc, ar, br, fk, wid, ge0, ge1);
    ktile<4, true, true>(A, B, rowBlk, colBlk, t + 1,
        sA10, sA11, sB10, sB11, sA01, sB00,
        acc, ar, br, fk, wid, ge0, ge1);
  }
  // tile 62 (parity 0): stage only t+1=63; drain vmcnt to 0 at boundary
  ktile<0, true, false>(A, B, rowBlk, colBlk, 62,
      sA00, sA01, sB00, sB01, sA11, sB10,
      acc, ar, br, fk, wid, ge0, ge1);
  // tile 63 (parity 1): compute only
  ktile<-1, false, false>(A, B, rowBlk, colBlk, 63,
      sA10, sA11, sB10, sB11, sA01, sB00,
      acc, ar, br, fk, wid, ge0, ge1);

  // ---- epilogue: y = acc*scale + bias; C/D: col=lane&15, row=(lane>>4)*4+j
  const float s = scale[0];
#pragma unroll
  for (int ni = 0; ni < 4; ++ni) {
    const int nh = ni >> 1, n = ni & 1;
    const int col = colBlk + nh * 128 + wn * 32 + n * 16 + fr;
    const float bv = bias[col];
#pragma unroll
    for (int mi = 0; mi < 8; ++mi) {
      const int mh = mi >> 2, m = mi & 3;
      const int row = rowBlk + mh * 128 + wm * 64 + m * 16 + fk * 4;
#pragma unroll
      for (int j = 0; j < 4; ++j)
        C[(size_t)(row + j) * OUTF + col] = acc[mi][ni][j] * s + bv;
    }
  }
}

// ---------------- fallback: R1 128x128 m97-structure GEMM -------------------
__global__ __launch_bounds__(256) void l2b_gemm(
    const ushort_t* __restrict__ A, const ushort_t* __restrict__ B,
    const float* __restrict__ scale, const float* __restrict__ bias,
    float* __restrict__ C) {
  constexpr int K = INF;
  constexpr int N = OUTF;
  __shared__ __align__(16) ushort_t ldsA[128 * 32];
  __shared__ __align__(16) ushort_t ldsB[128 * 32];
  const int tid = threadIdx.x;
  const int lane = tid & 63;
  const int wid = tid >> 6;
  const int wm = wid >> 1, wn = wid & 1;
  const int bm = blockIdx.x >> 5, bn = blockIdx.x & 31;
  const int row0 = bm * 128, col0 = bn * 128;
  const int lr = lane >> 4, lc = lane & 15;
  f32x4 acc[4][4] = {};
  for (int k0 = 0; k0 < K; k0 += 32) {
#pragma unroll
    for (int i = 0; i < 2; ++i) {
      const int idx = i * 256 + tid;
      const int r = idx >> 2;
      const int c = (idx & 3) * 8;
      ushort_t* lbaseA = ldsA + i * 2048 + wid * 512;
      ushort_t* lbaseB = ldsB + i * 2048 + wid * 512;
      gload_lds16(A + (size_t)(row0 + r) * K + (k0 + c), lbaseA);
      gload_lds16(B + (size_t)(col0 + r) * K + (k0 + c), lbaseB);
    }
    __syncthreads();
    bf16x8 af[4], bfr[4];
#pragma unroll
    for (int m = 0; m < 4; ++m)
      af[m] = *reinterpret_cast<const bf16x8*>(
          &ldsA[(wm * 64 + m * 16 + lc) * 32 + lr * 8]);
#pragma unroll
    for (int n = 0; n < 4; ++n)
      bfr[n] = *reinterpret_cast<const bf16x8*>(
          &ldsB[(wn * 64 + n * 16 + lc) * 32 + lr * 8]);
#pragma unroll
    for (int m = 0; m < 4; ++m)
#pragma unroll
      for (int n = 0; n < 4; ++n)
        acc[m][n] = mfma(af[m], bfr[n], acc[m][n]);
    __syncthreads();
  }
  const float s = scale[0];
#pragma unroll
  for (int n = 0; n < 4; ++n) {
    const int col = col0 + wn * 64 + n * 16 + lc;
    const float bv = bias[col];
#pragma unroll
    for (int m = 0; m < 4; ++m) {
      const int row = row0 + wm * 64 + m * 16 + lr * 4;
#pragma unroll
      for (int i = 0; i < 4; ++i)
        C[(size_t)(row + i) * N + col] = acc[m][n][i] * s + bv;
    }
  }
}

__global__ void l2b_naive(const float* __restrict__ x, const int* __restrict__ w,
                          const float* __restrict__ scale,
                          const float* __restrict__ bias,
                          float* __restrict__ out) {
  const int o = blockIdx.x * blockDim.x + threadIdx.x;
  if (o >= TOKENS * OUTF) return;
  const int t = o / OUTF;
  const int n = o - t * OUTF;
  const float* xr = x + (size_t)t * INF;
  const int* wr = w + (size_t)n * INF;
  float acc = 0.f;
  for (int k = 0; k < INF; ++k) acc += xr[k] * (float)wr[k];
  out[o] = acc * scale[0] + bias[n];
}

extern "C" void kernel_launch(void* const* d_in, const int* in_sizes, int n_in,
                              void* d_out, int out_size, void* d_ws, size_t ws_size,
                              hipStream_t stream) {
  const float* x     = (const float*)d_in[0];
  const int*   wq    = (const int*)d_in[1];
  const float* scale = (const float*)d_in[2];
  const float* bias  = (const float*)d_in[3];
  float* out = (float*)d_out;

  const size_t xbytes = (size_t)TOKENS * INF * 2;
  const size_t wbytes = (size_t)OUTF * INF * 2;

  if (ws_size >= xbytes + wbytes) {
    unsigned short* xb = (unsigned short*)d_ws;
    unsigned short* wb = (unsigned short*)((char*)d_ws + xbytes);
    l2b_conv_x<<<2048, 256, 0, stream>>>(x, xb, TOKENS * INF / 4);
    l2b_conv_w<<<2048, 256, 0, stream>>>(wq, wb, OUTF * INF / 4);

    hipError_t e = hipFuncSetAttribute(
        reinterpret_cast<const void*>(l2b_gemm8),
        hipFuncAttributeMaxDynamicSharedMemorySize, 131072);
    if (e == hipSuccess) {
      l2b_gemm8<<<dim3((TOKENS / 256) * (OUTF / 256)), 512, 131072, stream>>>(
          xb, wb, scale, bias, out);
    } else {
      l2b_gemm<<<dim3((TOKENS / 128) * (OUTF / 128)), 256, 0, stream>>>(
          xb, wb, scale, bias, out);
    }
  } else {
    l2b_naive<<<(TOKENS * OUTF + 255) / 256, 256, 0, stream>>>(
        x, wq, scale, bias, out);
  }
}